// Round 5
// baseline (342.267 us; speedup 1.0000x reference)
//
#include <hip/hip_runtime.h>

#define NB 8
#define NC 128
#define NM 4096

typedef __attribute__((ext_vector_type(8))) short short8;
typedef __attribute__((ext_vector_type(4))) float floatx4;

#define MFMA(a, b, c) __builtin_amdgcn_mfma_f32_16x16x32_bf16(a, b, c, 0, 0, 0)
#define EXP2F(x) __builtin_amdgcn_exp2f(x)

union S8U { short8 v; uint2 u2[2]; };

__device__ __forceinline__ unsigned pack2bf(float a, float b) {
    unsigned ua = __float_as_uint(a);
    unsigned ub = __float_as_uint(b);
    ua += 0x7fffu + ((ua >> 16) & 1u);
    ub += 0x7fffu + ((ub >> 16) & 1u);
    return (ua >> 16) | (ub & 0xffff0000u);
}

__device__ __forceinline__ void fma4(float4& a, float s, const float4& v) {
    a.x += s * v.x; a.y += s * v.y; a.z += s * v.z; a.w += s * v.w;
}

// ---------------------------------------------------------------------------
// P1: fT[b][m][c] = bf16( f[b][c][m] * sqrt(C^-1/2 * log2e) )
// ---------------------------------------------------------------------------
__global__ __launch_bounds__(256) void prep_ft(
    const float* __restrict__ f, unsigned short* __restrict__ fT)
{
    __shared__ float Ls[128][65];
    const int tid = threadIdx.x;
    const int b   = blockIdx.x & 7;
    const int m0  = (blockIdx.x >> 3) << 6;
    const float* fb = f + (size_t)b * NC * NM;
    #pragma unroll
    for (int k = 0; k < 32; ++k) {
        int idx = tid + (k << 8);
        int c = idx >> 6, mm = idx & 63;
        Ls[c][mm] = fb[(size_t)c * NM + m0 + mm];
    }
    __syncthreads();
    const float SQ = 0.35712442f;   // sqrt(2^-3.5 * log2(e))
    const int m  = tid >> 2;
    const int ch = (tid & 3) << 5;
    unsigned pk[16];
    #pragma unroll
    for (int i = 0; i < 16; ++i)
        pk[i] = pack2bf(Ls[ch + 2 * i][m] * SQ, Ls[ch + 2 * i + 1][m] * SQ);
    unsigned short* dst = fT + ((size_t)b * NM + m0 + m) * NC + ch;
    #pragma unroll
    for (int i = 0; i < 4; ++i)
        ((uint4*)dst)[i] = make_uint4(pk[4 * i], pk[4 * i + 1], pk[4 * i + 2], pk[4 * i + 3]);
}

// ---------------------------------------------------------------------------
// P2a: gN[b][o][n] = bf16( sum_c w1[o,c] f[b,c,n] ), o in [0,128)
// grid 256 = b(8) x nt(4) x oc(8); 256 thr, 4 n x 16 o each.
// ---------------------------------------------------------------------------
__global__ __launch_bounds__(256) void prep_g(
    const float* __restrict__ f, const float* __restrict__ w1,
    unsigned short* __restrict__ gN)
{
    __shared__ float Ws[128][16];
    const int tid = threadIdx.x;
    const int b   = blockIdx.x & 7;
    const int nt  = (blockIdx.x >> 3) & 3;
    const int oc  = blockIdx.x >> 5;         // 0..7
    const int n0  = nt << 10;
    const int o0  = oc << 4;
    for (int i = tid; i < 128 * 16; i += 256) {
        int c = i >> 4, k = i & 15;
        Ws[c][k] = w1[(o0 + k) * 256 + c];
    }
    __syncthreads();

    const float* fb = f + (size_t)b * NC * NM + n0 + (tid << 2);
    float4 acc[16];
    #pragma unroll
    for (int j = 0; j < 16; ++j) acc[j] = make_float4(0.f, 0.f, 0.f, 0.f);

    for (int c = 0; c < NC; ++c) {
        float4 fv = *(const float4*)(fb + (size_t)c * NM);
        const float4* wq = (const float4*)&Ws[c][0];
        float4 w0 = wq[0], w1q = wq[1], w2q = wq[2], w3q = wq[3];
        fma4(acc[0],  w0.x,  fv); fma4(acc[1],  w0.y,  fv);
        fma4(acc[2],  w0.z,  fv); fma4(acc[3],  w0.w,  fv);
        fma4(acc[4],  w1q.x, fv); fma4(acc[5],  w1q.y, fv);
        fma4(acc[6],  w1q.z, fv); fma4(acc[7],  w1q.w, fv);
        fma4(acc[8],  w2q.x, fv); fma4(acc[9],  w2q.y, fv);
        fma4(acc[10], w2q.z, fv); fma4(acc[11], w2q.w, fv);
        fma4(acc[12], w3q.x, fv); fma4(acc[13], w3q.y, fv);
        fma4(acc[14], w3q.z, fv); fma4(acc[15], w3q.w, fv);
    }

    #pragma unroll
    for (int j = 0; j < 16; ++j) {
        unsigned lo = pack2bf(acc[j].x, acc[j].y);
        unsigned hi = pack2bf(acc[j].z, acc[j].w);
        *(uint2*)(gN + ((size_t)b * NC + o0 + j) * NM + n0 + (tid << 2)) =
            make_uint2(lo, hi);
    }
}

// ---------------------------------------------------------------------------
// P2b: hT[b][n][o] = f32( sum_c w1[o,128+c] f[b,c,n] ), full 128-o row per
// thread -> fully coalesced 512B/thread stores. grid 128 = b(8) x nt(16).
// ---------------------------------------------------------------------------
__global__ __launch_bounds__(256) void prep_h(
    const float* __restrict__ f, const float* __restrict__ w1,
    float* __restrict__ hT)
{
    __shared__ float Wl[128][128];   // [c][o], reads are wave-broadcast
    const int tid = threadIdx.x;
    const int b   = blockIdx.x & 7;
    const int n0  = (blockIdx.x >> 3) << 8;

    for (int i = tid; i < 128 * 128; i += 256) {
        int o = i >> 7, c = i & 127;
        Wl[c][o] = w1[o * 256 + NC + c];
    }
    __syncthreads();

    const float* fb = f + (size_t)b * NC * NM + n0 + tid;
    float4 acc[32];
    #pragma unroll
    for (int j = 0; j < 32; ++j) acc[j] = make_float4(0.f, 0.f, 0.f, 0.f);

    for (int c = 0; c < NC; ++c) {
        float fv = fb[(size_t)c * NM];
        const float4* wrow = (const float4*)&Wl[c][0];
        #pragma unroll
        for (int j = 0; j < 32; ++j) fma4(acc[j], fv, wrow[j]);
    }

    float4* dst = (float4*)(hT + ((size_t)b * NM + n0 + tid) * NC);
    #pragma unroll
    for (int j = 0; j < 32; ++j) dst[j] = acc[j];
}

// ---------------------------------------------------------------------------
// Main: barrier-free MFMA flash attention + fused cls head.
// grid 512 = b(8) x mblock(64); 256 thr = 4 waves, 1 wave/SIMD (~370 regs).
// Wave w owns n-stripe {it*128 + w*16, it*128 + 64 + w*16}; P passes from
// exp2 registers directly into PV A-operands (k=8q+j -> {A:4q+j, B:4q+j-4}).
// Split-K partial u/l per wave, one LDS reduction at the end.
// ---------------------------------------------------------------------------
__global__ __launch_bounds__(256) void attn_kernel(
    const unsigned short* __restrict__ fT,
    const unsigned short* __restrict__ gN,
    const float* __restrict__ hT,
    const float* __restrict__ b1v, const float* __restrict__ gammav,
    const float* __restrict__ betav, const float* __restrict__ rmeanv,
    const float* __restrict__ rvarv, const float* __restrict__ w2v,
    const float* __restrict__ b2v, float* __restrict__ out)
{
    __shared__ float Up[4][16][130];   // [wave][m_local][o]
    __shared__ float Lp[4][16];

    const int tid = threadIdx.x;
    const int w   = tid >> 6;
    const int l   = tid & 63;
    const int lm  = l & 15;
    const int lq  = l >> 4;
    const int b   = blockIdx.x & 7;
    const int m0  = (blockIdx.x >> 3) << 6;

    const unsigned short* fTb = fT + (size_t)b * NM * NC;
    const unsigned short* gNb = gN + (size_t)b * NC * NM;

    // stationary Q B-frags: qf[mt][ks] covers m = m0+mt*16+lm, c = ks*32+lq*8
    short8 qf[4][4];
    {
        const unsigned short* qp = fTb + (size_t)(m0 + lm) * NC + lq * 8;
        #pragma unroll
        for (int mt = 0; mt < 4; ++mt)
            #pragma unroll
            for (int ks = 0; ks < 4; ++ks)
                qf[mt][ks] = *(const short8*)(qp + mt * 16 * NC + ks * 32);
    }

    short8 ones;
    #pragma unroll
    for (int j = 0; j < 8; ++j) ones[j] = (short)0x3F80;   // bf16 1.0

    // K row pointers: nA = it*128 + w*16 + lm ; nB = nA + 64
    const unsigned short* kpA = fTb + (size_t)(w * 16 + lm) * NC + lq * 8;
    const unsigned short* kpB = kpA + (size_t)64 * NC;

    // G base pointers: row o = ot*16+lm, col = it*128 + w*16 + lq*4 (+64 for B)
    const unsigned short* gp[8];
    #pragma unroll
    for (int ot = 0; ot < 8; ++ot)
        gp[ot] = gNb + (size_t)(ot * 16 + lm) * NM + w * 16 + lq * 4;

    short8 kfA[4], kfB[4], gb[8];
    #pragma unroll
    for (int ks = 0; ks < 4; ++ks) {
        kfA[ks] = *(const short8*)(kpA + ks * 32);
        kfB[ks] = *(const short8*)(kpB + ks * 32);
    }
    #pragma unroll
    for (int ot = 0; ot < 8; ++ot) {
        S8U t;
        t.u2[0] = *(const uint2*)(gp[ot]);
        t.u2[1] = *(const uint2*)(gp[ot] + 64);
        gb[ot] = t.v;
    }

    floatx4 u[4][8];
    floatx4 lones[4];
    #pragma unroll
    for (int mt = 0; mt < 4; ++mt) {
        lones[mt] = (floatx4){0.f, 0.f, 0.f, 0.f};
        #pragma unroll
        for (int ot = 0; ot < 8; ++ot) u[mt][ot] = (floatx4){0.f, 0.f, 0.f, 0.f};
    }

    #pragma unroll 1
    for (int it = 0; it < 32; ++it) {
        // ---- S^T tiles (two per wave), acc seeded -24 ----
        floatx4 svA[4], svB[4];
        #pragma unroll
        for (int mt = 0; mt < 4; ++mt) {
            floatx4 a = {-24.f, -24.f, -24.f, -24.f};
            floatx4 bb = {-24.f, -24.f, -24.f, -24.f};
            #pragma unroll
            for (int ks = 0; ks < 4; ++ks) {
                a  = MFMA(kfA[ks], qf[mt][ks], a);
                bb = MFMA(kfB[ks], qf[mt][ks], bb);
            }
            svA[mt] = a; svB[mt] = bb;
        }
        // prefetch next K (consumed next iter top)
        {
            const int kstep = (it < 31) ? 128 * NC : 0;
            kpA += kstep; kpB += kstep;
            #pragma unroll
            for (int ks = 0; ks < 4; ++ks) {
                kfA[ks] = *(const short8*)(kpA + ks * 32);
                kfB[ks] = *(const short8*)(kpB + ks * 32);
            }
        }

        // ---- p = exp2(s); pack directly into PV A-frags ----
        short8 pf[4];
        #pragma unroll
        for (int mt = 0; mt < 4; ++mt) {
            S8U t;
            t.u2[0] = make_uint2(
                pack2bf(EXP2F(svA[mt][0]), EXP2F(svA[mt][1])),
                pack2bf(EXP2F(svA[mt][2]), EXP2F(svA[mt][3])));
            t.u2[1] = make_uint2(
                pack2bf(EXP2F(svB[mt][0]), EXP2F(svB[mt][1])),
                pack2bf(EXP2F(svB[mt][2]), EXP2F(svB[mt][3])));
            pf[mt] = t.v;
        }

        // ---- PV + l: u += P*G, l += P*ones ----
        #pragma unroll
        for (int ot = 0; ot < 8; ++ot)
            #pragma unroll
            for (int mt = 0; mt < 4; ++mt)
                u[mt][ot] = MFMA(pf[mt], gb[ot], u[mt][ot]);
        #pragma unroll
        for (int mt = 0; mt < 4; ++mt)
            lones[mt] = MFMA(pf[mt], ones, lones[mt]);

        // prefetch next G (consumed next iter PV)
        {
            const int gstep = (it < 31) ? 128 : 0;
            #pragma unroll
            for (int ot = 0; ot < 8; ++ot) {
                gp[ot] += gstep;
                S8U t;
                t.u2[0] = *(const uint2*)(gp[ot]);
                t.u2[1] = *(const uint2*)(gp[ot] + 64);
                gb[ot] = t.v;
            }
        }
    }

    // ---- epilogue: cross-wave reduction + BN + leaky + w2 dot ----
    float A8[8], D8[8], W28[8];
    {
        const int ob = (tid & 15) << 3;
        #pragma unroll
        for (int j = 0; j < 8; ++j) {
            int o = ob + j;
            float Ar = gammav[o] * rsqrtf(rvarv[o] + 1e-5f);
            A8[j] = Ar;
            D8[j] = (b1v[o] - rmeanv[o]) * Ar + betav[o];
            W28[j] = w2v[o];
        }
    }
    const float b2s = b2v[0];
    const int ml = tid >> 4;
    const int oc = (tid & 15) << 3;

    for (int mt = 0; mt < 4; ++mt) {
        __syncthreads();
        #pragma unroll
        for (int ot = 0; ot < 8; ++ot)
            #pragma unroll
            for (int r = 0; r < 4; ++r)
                Up[w][lq * 4 + r][ot * 16 + lm] = u[mt][ot][r];
        if (lm == 0) {
            #pragma unroll
            for (int r = 0; r < 4; ++r) Lp[w][lq * 4 + r] = lones[mt][r];
        }
        __syncthreads();

        float rl = 1.f / (Lp[0][ml] + Lp[1][ml] + Lp[2][ml] + Lp[3][ml]);
        const float* hp = hT + ((size_t)b * NM + m0 + mt * 16 + ml) * NC + oc;
        float acc = 0.f;
        #pragma unroll
        for (int j = 0; j < 8; ++j) {
            float us = Up[0][ml][oc + j] + Up[1][ml][oc + j] +
                       Up[2][ml][oc + j] + Up[3][ml][oc + j];
            float t = A8[j] * (us * rl + hp[j]) + D8[j];
            t = t >= 0.f ? t : 0.01f * t;
            acc += W28[j] * t;
        }
        acc += __shfl_xor(acc, 1);
        acc += __shfl_xor(acc, 2);
        acc += __shfl_xor(acc, 4);
        acc += __shfl_xor(acc, 8);
        if ((tid & 15) == 0)
            out[(size_t)b * NM + m0 + mt * 16 + ml] = acc + b2s;
    }
}

extern "C" void kernel_launch(void* const* d_in, const int* in_sizes, int n_in,
                              void* d_out, int out_size, void* d_ws, size_t ws_size,
                              hipStream_t stream) {
    const float* f     = (const float*)d_in[0];
    const float* w1    = (const float*)d_in[1];
    const float* b1    = (const float*)d_in[2];
    const float* gamma = (const float*)d_in[3];
    const float* beta  = (const float*)d_in[4];
    const float* rmean = (const float*)d_in[5];
    const float* rvar  = (const float*)d_in[6];
    const float* w2    = (const float*)d_in[7];
    const float* b2    = (const float*)d_in[8];
    float* out = (float*)d_out;

    unsigned short* fT = (unsigned short*)d_ws;              // 8 MB bf16 [b][m][c]
    unsigned short* gN = fT + (size_t)NB * NM * NC;          // 8 MB bf16 [b][o][n]
    float*          hT = (float*)(gN + (size_t)NB * NC * NM);// 16 MB f32 [b][m][o]

    hipLaunchKernelGGL(prep_ft, dim3(512), dim3(256), 0, stream, f, fT);
    hipLaunchKernelGGL(prep_g,  dim3(256), dim3(256), 0, stream, f, w1, gN);
    hipLaunchKernelGGL(prep_h,  dim3(128), dim3(256), 0, stream, f, w1, hT);
    hipLaunchKernelGGL(attn_kernel, dim3(512), dim3(256), 0, stream,
                       fT, gN, hT, b1, gamma, beta, rmean, rvar, w2, b2, out);
}